// Round 1
// baseline (953.865 us; speedup 1.0000x reference)
//
#include <hip/hip_runtime.h>
#include <stdint.h>

// Problem constants (Switch MoE eval): B=2,S=4096,D=1024,E=8,H=4*D, T=B*S
#define T_TOK 8192
#define D_DIM 1024
#define E_NUM 8
#define H_DIM 4096
#define CAPQ  1280   // int(1.25*T/E)
#define CAPR  1280   // padded rows per expert (multiple of 128)
#define MT_MAX 10    // CAPR/128

typedef __bf16 bf16x8 __attribute__((ext_vector_type(8)));
typedef float  f32x4  __attribute__((ext_vector_type(4)));
typedef const __attribute__((address_space(1))) void glb_void;
typedef __attribute__((address_space(3))) void lds_void;

__device__ __forceinline__ unsigned short f2bf(float f) {
  union { float f; unsigned u; } v; v.f = f;
  return (unsigned short)((v.u + 0x7FFFu + ((v.u >> 16) & 1u)) >> 16);
}

// ---------------- router: logits, softmax, gate/eidx, counts, entropy ----------------
__global__ __launch_bounds__(256) void router_kernel(
    const float* __restrict__ x, const float* __restrict__ rw,
    float* __restrict__ gate, int* __restrict__ eidx,
    int* __restrict__ cnt, float* __restrict__ entacc)
{
  __shared__ float wl[E_NUM * D_DIM];           // 32 KB router weights
  __shared__ float sent[4];
  const int tid = threadIdx.x;
  for (int i = tid; i < E_NUM * D_DIM / 4; i += 256)
    ((float4*)wl)[i] = ((const float4*)rw)[i];
  __syncthreads();

  const int wid = tid >> 6, lane = tid & 63;
  const int t = blockIdx.x * 4 + wid;
  float acc[E_NUM];
#pragma unroll
  for (int e = 0; e < E_NUM; ++e) acc[e] = 0.f;
  const float* xr = x + (size_t)t * D_DIM;
  for (int k = 0; k < D_DIM / 64; ++k) {
    float xv = xr[k * 64 + lane];
#pragma unroll
    for (int e = 0; e < E_NUM; ++e) acc[e] += xv * wl[e * D_DIM + k * 64 + lane];
  }
#pragma unroll
  for (int e = 0; e < E_NUM; ++e) {
#pragma unroll
    for (int off = 32; off; off >>= 1) acc[e] += __shfl_xor(acc[e], off);
  }
  float entv = 0.f;
  if (lane == 0) {
    float mx = acc[0]; int am = 0;
#pragma unroll
    for (int e = 1; e < E_NUM; ++e) if (acc[e] > mx) { mx = acc[e]; am = e; }
    float p[E_NUM], s = 0.f;
#pragma unroll
    for (int e = 0; e < E_NUM; ++e) { p[e] = __expf(acc[e] - mx); s += p[e]; }
    const float inv = 1.f / s;
    float g = 0.f, ent = 0.f;
#pragma unroll
    for (int e = 0; e < E_NUM; ++e) {
      float pe = p[e] * inv;
      ent -= pe * __logf(pe + 1e-8f);
      if (e == am) g = pe;
    }
    gate[t] = g;
    eidx[t] = am;
    atomicAdd(&cnt[am], 1);
    entv = ent * (1.0f / T_TOK);
  }
  if (lane == 0) sent[wid] = entv;
  __syncthreads();
  if (tid == 0) atomicAdd(entacc, sent[0] + sent[1] + sent[2] + sent[3]);
}

// ---------------- dispatch: slot assign + gather-convert x -> xs (bf16) ----------------
__global__ __launch_bounds__(256) void dispatch_kernel(
    const float* __restrict__ x, const int* __restrict__ eidx,
    int* __restrict__ cursor, int* __restrict__ perm,
    unsigned short* __restrict__ xs)
{
  const int tid = threadIdx.x, wid = tid >> 6, lane = tid & 63;
  const int t = blockIdx.x * 4 + wid;
  const int e = eidx[t];
  int slot = 0;
  if (lane == 0) slot = atomicAdd(&cursor[e], 1);
  slot = __shfl(slot, 0);
  if (slot >= CAPQ) return;   // dropped (never happens for this input; out pre-zeroed)
  if (lane == 0) perm[e * CAPR + slot] = t;
  const float4* xr = (const float4*)(x + (size_t)t * D_DIM);
  unsigned short* dst = xs + ((size_t)e * CAPR + slot) * D_DIM;
#pragma unroll
  for (int i = 0; i < 4; ++i) {
    float4 v = xr[i * 64 + lane];
    ushort4 o;
    o.x = f2bf(v.x); o.y = f2bf(v.y); o.z = f2bf(v.z); o.w = f2bf(v.w);
    ((ushort4*)dst)[i * 64 + lane] = o;
  }
}

// ---------------- transpose-convert: fp32 [E][R][C] -> bf16 [E][C][R] ----------------
template<int R, int C>
__global__ __launch_bounds__(256) void transpose_conv(
    const float* __restrict__ src, unsigned short* __restrict__ dst)
{
  __shared__ float tl[32][33];
  const int e = blockIdx.z;
  const float* s = src + (size_t)e * R * C;
  unsigned short* d = dst + (size_t)e * R * C;
  const int tx = threadIdx.x, ty = threadIdx.y;   // (32, 8)
  const int c0 = blockIdx.x * 32, r0 = blockIdx.y * 32;
#pragma unroll
  for (int i = 0; i < 4; ++i)
    tl[ty + i * 8][tx] = s[(size_t)(r0 + ty + i * 8) * C + c0 + tx];
  __syncthreads();
#pragma unroll
  for (int i = 0; i < 4; ++i)
    d[(size_t)(c0 + ty + i * 8) * R + r0 + tx] = f2bf(tl[tx][ty + i * 8]);
}

// ---------------- grouped GEMM: C[128x128] per block, bf16 MFMA 16x16x32 ----------------
// A: [E][CAPR][K] bf16 row-major (K-minor). Bt: [E][N][K] bf16 (K-minor).
// EPI 0: h = relu(acc + b1) -> bf16 hout[E][CAPR][N]
// EPI 1: out[tok] = (acc + b2) * gate[tok], tok = perm[e*CAPR+row]
template<int K, int N, int EPI>
__global__ __launch_bounds__(256, 2) void gemm_moe(
    const unsigned short* __restrict__ A,
    const unsigned short* __restrict__ Bt,
    const float* __restrict__ bias,
    const int* __restrict__ cnt,
    unsigned short* __restrict__ hout,
    float* __restrict__ out,
    const int* __restrict__ perm,
    const float* __restrict__ gate)
{
  __shared__ __align__(16) unsigned short As[2][128 * 64];
  __shared__ __align__(16) unsigned short Bs[2][128 * 64];

  const int e = blockIdx.z;
  int c = cnt[e]; if (c > CAPQ) c = CAPQ;
  const int row0 = blockIdx.y * 128;
  if (row0 >= c) return;                 // whole block exits together
  const int n0 = blockIdx.x * 128;

  const int tid = threadIdx.x;
  const int wid = tid >> 6, lane = tid & 63;
  const int wm = wid >> 1, wn = wid & 1;            // 2x2 wave grid, 64x64 per wave
  const int srow = wid * 32 + (lane >> 3);          // staging row (+ i*8)
  const int sk = (lane & 7) * 8;                    // staging k offset (16B granules)
  const int fr = lane & 15, fk = (lane >> 4) * 8;   // fragment row/col + k offset

  const unsigned short* Abase = A + ((size_t)e * CAPR + row0) * K;
  const unsigned short* Bbase = Bt + ((size_t)e * N + n0) * K;

  f32x4 acc[4][4];
#pragma unroll
  for (int m = 0; m < 4; ++m)
#pragma unroll
    for (int n = 0; n < 4; ++n) acc[m][n] = f32x4{0.f, 0.f, 0.f, 0.f};

  // prologue: stage K-tile 0
#pragma unroll
  for (int i = 0; i < 4; ++i) {
    __builtin_amdgcn_global_load_lds(
        (glb_void*)(Abase + (size_t)(srow + i * 8) * K + sk),
        (lds_void*)(&As[0][wid * 2048 + i * 512]), 16, 0, 0);
    __builtin_amdgcn_global_load_lds(
        (glb_void*)(Bbase + (size_t)(srow + i * 8) * K + sk),
        (lds_void*)(&Bs[0][wid * 2048 + i * 512]), 16, 0, 0);
  }
  asm volatile("s_waitcnt vmcnt(0)" ::: "memory");
  __syncthreads();

  int cur = 0;
  const int NT = K / 64;
  for (int t = 0; t < NT; ++t) {
    if (t + 1 < NT) {
      const int ko = (t + 1) * 64;
#pragma unroll
      for (int i = 0; i < 4; ++i) {
        __builtin_amdgcn_global_load_lds(
            (glb_void*)(Abase + (size_t)(srow + i * 8) * K + ko + sk),
            (lds_void*)(&As[cur ^ 1][wid * 2048 + i * 512]), 16, 0, 0);
        __builtin_amdgcn_global_load_lds(
            (glb_void*)(Bbase + (size_t)(srow + i * 8) * K + ko + sk),
            (lds_void*)(&Bs[cur ^ 1][wid * 2048 + i * 512]), 16, 0, 0);
      }
    }
    const unsigned short* Ap = As[cur];
    const unsigned short* Bp = Bs[cur];
#pragma unroll
    for (int kk = 0; kk < 2; ++kk) {
      bf16x8 af[4], bfm[4];
#pragma unroll
      for (int m = 0; m < 4; ++m)
        af[m] = *(const bf16x8*)(Ap + ((wm * 64 + m * 16 + fr) * 64 + kk * 32 + fk));
#pragma unroll
      for (int n = 0; n < 4; ++n)
        bfm[n] = *(const bf16x8*)(Bp + ((wn * 64 + n * 16 + fr) * 64 + kk * 32 + fk));
#pragma unroll
      for (int m = 0; m < 4; ++m)
#pragma unroll
        for (int n = 0; n < 4; ++n)
          acc[m][n] = __builtin_amdgcn_mfma_f32_16x16x32_bf16(af[m], bfm[n], acc[m][n], 0, 0, 0);
    }
    asm volatile("s_waitcnt vmcnt(0)" ::: "memory");
    __syncthreads();
    cur ^= 1;
  }

  // epilogue: C layout col = lane&15, row = (lane>>4)*4 + j   [measured m89/m91]
  const int frow = (lane >> 4) * 4;
  const int fcol = lane & 15;
#pragma unroll
  for (int m = 0; m < 4; ++m) {
#pragma unroll
    for (int n = 0; n < 4; ++n) {
      const int col = n0 + wn * 64 + n * 16 + fcol;
      const float bv = bias[e * N + col];
      if (EPI == 0) {
#pragma unroll
        for (int j = 0; j < 4; ++j) {
          const int r = wm * 64 + m * 16 + frow + j;
          float v = acc[m][n][j] + bv;
          v = v > 0.f ? v : 0.f;
          hout[((size_t)e * CAPR + row0 + r) * N + col] = f2bf(v);
        }
      } else {
#pragma unroll
        for (int j = 0; j < 4; ++j) {
          const int r = row0 + wm * 64 + m * 16 + frow + j;
          const int tok = perm[e * CAPR + r];
          if (tok >= 0)
            out[(size_t)tok * N + col] = (acc[m][n][j] + bv) * gate[tok];
        }
      }
    }
  }
}

// ---------------- finalize: entropy scalar + assignment counts ----------------
__global__ void finalize_kernel(const float* __restrict__ entacc,
                                const int* __restrict__ cnt,
                                float* __restrict__ tail)
{
  const int i = threadIdx.x;
  if (i == 0) tail[0] = *entacc;
  if (i < E_NUM) tail[1 + i] = (float)cnt[i];
}

extern "C" void kernel_launch(void* const* d_in, const int* in_sizes, int n_in,
                              void* d_out, int out_size, void* d_ws, size_t ws_size,
                              hipStream_t stream) {
  const float* x  = (const float*)d_in[0];
  const float* rw = (const float*)d_in[1];
  const float* W1 = (const float*)d_in[2];
  const float* b1 = (const float*)d_in[3];
  const float* W2 = (const float*)d_in[4];
  const float* b2 = (const float*)d_in[5];
  float* out = (float*)d_out;

  char* ws = (char*)d_ws;
  size_t off = 0;
  auto alloc = [&](size_t bytes) -> void* {
    void* p = ws + off;
    off = (off + bytes + 255) & ~(size_t)255;
    return p;
  };
  // WT shared between W1T (GEMM1) and W2T (GEMM2) — transposed after GEMM1 finishes.
  unsigned short* WT   = (unsigned short*)alloc((size_t)E_NUM * D_DIM * H_DIM * 2); // 67 MB
  unsigned short* xs   = (unsigned short*)alloc((size_t)E_NUM * CAPR * D_DIM * 2);  // 21 MB
  unsigned short* h    = (unsigned short*)alloc((size_t)E_NUM * CAPR * H_DIM * 2);  // 80 MB
  float* gate   = (float*)alloc(T_TOK * 4);
  int*   eidx   = (int*)alloc(T_TOK * 4);
  int*   perm   = (int*)alloc(E_NUM * CAPR * 4);
  int*   cnt    = (int*)alloc(256);
  int*   cursor = (int*)alloc(256);
  float* entacc = (float*)alloc(256);

  hipMemsetAsync(d_out, 0, (size_t)out_size * 4, stream);       // dropped tokens -> 0
  hipMemsetAsync(xs, 0, (size_t)E_NUM * CAPR * D_DIM * 2, stream); // zero-pad tails
  hipMemsetAsync(perm, 0xFF, E_NUM * CAPR * 4, stream);         // -1 = invalid row
  hipMemsetAsync(cnt, 0, 256, stream);
  hipMemsetAsync(cursor, 0, 256, stream);
  hipMemsetAsync(entacc, 0, 256, stream);

  router_kernel<<<T_TOK / 4, 256, 0, stream>>>(x, rw, gate, eidx, cnt, entacc);
  dispatch_kernel<<<T_TOK / 4, 256, 0, stream>>>(x, eidx, cursor, perm, xs);

  // W1 [E][D][H] -> WT [E][H][D]
  transpose_conv<D_DIM, H_DIM><<<dim3(H_DIM / 32, D_DIM / 32, E_NUM), dim3(32, 8), 0, stream>>>(W1, WT);
  gemm_moe<D_DIM, H_DIM, 0><<<dim3(H_DIM / 128, MT_MAX, E_NUM), 256, 0, stream>>>(
      xs, WT, b1, cnt, h, nullptr, nullptr, nullptr);

  // W2 [E][H][D] -> WT [E][D][H]
  transpose_conv<H_DIM, D_DIM><<<dim3(D_DIM / 32, H_DIM / 32, E_NUM), dim3(32, 8), 0, stream>>>(W2, WT);
  gemm_moe<H_DIM, D_DIM, 1><<<dim3(D_DIM / 128, MT_MAX, E_NUM), 256, 0, stream>>>(
      h, WT, b2, cnt, nullptr, out, perm, gate);

  finalize_kernel<<<1, 64, 0, stream>>>(entacc, cnt, out + (size_t)T_TOK * D_DIM);
}

// Round 2
// 848.043 us; speedup vs baseline: 1.1248x; 1.1248x over previous
//
#include <hip/hip_runtime.h>
#include <stdint.h>

// Problem constants (Switch MoE eval): B=2,S=4096,D=1024,E=8,H=4*D, T=B*S
#define T_TOK 8192
#define D_DIM 1024
#define E_NUM 8
#define H_DIM 4096
#define CAPQ  1280   // int(1.25*T/E)
#define CAPR  1280   // padded rows per expert (multiple of 128)
#define MT_MAX 10    // CAPR/128

typedef __bf16 bf16x8 __attribute__((ext_vector_type(8)));
typedef float  f32x4  __attribute__((ext_vector_type(4)));
typedef unsigned short u16x8 __attribute__((ext_vector_type(8)));
typedef unsigned short u16x4 __attribute__((ext_vector_type(4)));
typedef const __attribute__((address_space(1))) void glb_void;
typedef __attribute__((address_space(3))) void lds_void;

__device__ __forceinline__ unsigned short f2bf(float f) {
  union { float f; unsigned u; } v; v.f = f;
  return (unsigned short)((v.u + 0x7FFFu + ((v.u >> 16) & 1u)) >> 16);
}

// ------------- fused router + dispatch: one wave per token -------------
// logits -> softmax -> gate/argmax -> slot (atomic) -> gather-convert x row
__global__ __launch_bounds__(256) void router_dispatch_kernel(
    const float* __restrict__ x, const float* __restrict__ rw,
    float* __restrict__ gate, int* __restrict__ cnt, float* __restrict__ entacc,
    int* __restrict__ perm, unsigned short* __restrict__ xs)
{
  __shared__ float wl[E_NUM * D_DIM];           // 32 KB router weights
  __shared__ float sent[4];
  const int tid = threadIdx.x;
  for (int i = tid; i < E_NUM * D_DIM / 4; i += 256)
    ((float4*)wl)[i] = ((const float4*)rw)[i];
  __syncthreads();

  const int wid = tid >> 6, lane = tid & 63;
  const int t = blockIdx.x * 4 + wid;
  const float4* xr = (const float4*)(x + (size_t)t * D_DIM);
  float4 xv[4];
  float acc[E_NUM];
#pragma unroll
  for (int e = 0; e < E_NUM; ++e) acc[e] = 0.f;
#pragma unroll
  for (int k = 0; k < 4; ++k) {
    xv[k] = xr[k * 64 + lane];
#pragma unroll
    for (int e = 0; e < E_NUM; ++e) {
      float4 w = ((const float4*)wl)[e * 256 + k * 64 + lane];
      acc[e] += xv[k].x * w.x + xv[k].y * w.y + xv[k].z * w.z + xv[k].w * w.w;
    }
  }
#pragma unroll
  for (int e = 0; e < E_NUM; ++e) {
#pragma unroll
    for (int off = 32; off; off >>= 1) acc[e] += __shfl_xor(acc[e], off);
  }
  int am = 0, slot = 0;
  float entv = 0.f;
  if (lane == 0) {
    float mx = acc[0];
#pragma unroll
    for (int e = 1; e < E_NUM; ++e) if (acc[e] > mx) { mx = acc[e]; am = e; }
    float p[E_NUM], s = 0.f;
#pragma unroll
    for (int e = 0; e < E_NUM; ++e) { p[e] = __expf(acc[e] - mx); s += p[e]; }
    const float inv = 1.f / s;
    float g = 0.f, ent = 0.f;
#pragma unroll
    for (int e = 0; e < E_NUM; ++e) {
      float pe = p[e] * inv;
      ent -= pe * __logf(pe + 1e-8f);
      if (e == am) g = pe;
    }
    gate[t] = g;
    slot = atomicAdd(&cnt[am], 1);
    entv = ent * (1.0f / T_TOK);
  }
  am = __shfl(am, 0);
  slot = __shfl(slot, 0);
  if (slot < CAPQ) {
    if (lane == 0) perm[am * CAPR + slot] = t;
    unsigned short* dst = xs + ((size_t)am * CAPR + slot) * D_DIM;
#pragma unroll
    for (int k = 0; k < 4; ++k) {
      u16x4 o;
      o[0] = f2bf(xv[k].x); o[1] = f2bf(xv[k].y);
      o[2] = f2bf(xv[k].z); o[3] = f2bf(xv[k].w);
      *(u16x4*)(dst + k * 256 + lane * 4) = o;
    }
  }
  if (lane == 0) sent[wid] = entv;
  __syncthreads();
  if (tid == 0) atomicAdd(entacc, sent[0] + sent[1] + sent[2] + sent[3]);
}

// ------------- transpose-convert: fp32 [E][R][C] -> bf16 [E][C][R] -------------
// 64x64 tile: float4 coalesced loads, ushort8 coalesced stores.
template<int R, int C>
__global__ __launch_bounds__(256) void transpose_conv(
    const float* __restrict__ src, unsigned short* __restrict__ dst)
{
  __shared__ float tl[64][65];
  const int e = blockIdx.z;
  const float* s = src + (size_t)e * R * C;
  unsigned short* d = dst + (size_t)e * R * C;
  const int tid = threadIdx.x;
  const int c0 = blockIdx.x * 64, r0 = blockIdx.y * 64;
  const int lr = tid >> 4, lc = (tid & 15) * 4;
#pragma unroll
  for (int i = 0; i < 4; ++i) {
    float4 v = *(const float4*)(s + (size_t)(r0 + lr + i * 16) * C + c0 + lc);
    tl[lr + i * 16][lc + 0] = v.x; tl[lr + i * 16][lc + 1] = v.y;
    tl[lr + i * 16][lc + 2] = v.z; tl[lr + i * 16][lc + 3] = v.w;
  }
  __syncthreads();
  const int oc = tid >> 3, orr = (tid & 7) * 8;
#pragma unroll
  for (int p = 0; p < 2; ++p) {
    const int cc = oc + p * 32;
    u16x8 o;
#pragma unroll
    for (int j = 0; j < 8; ++j) o[j] = f2bf(tl[orr + j][cc]);
    *(u16x8*)(d + (size_t)(c0 + cc) * R + r0 + orr) = o;
  }
}

// ------------- grouped GEMM: 128x128/block, bf16 MFMA 16x16x32, single-buffer -------------
// A: [E][CAPR][K] bf16 (K-minor). Bt: [E][N][K] bf16 (K-minor).
// EPI 0: h = relu(acc + b1) -> bf16 hout[E][CAPR][N]
// EPI 1: out[tok] = (acc + b2) * gate[tok], tok = perm[e*CAPR+row]
template<int K, int N, int EPI>
__global__ __launch_bounds__(256, 5) void gemm_moe(
    const unsigned short* __restrict__ A,
    const unsigned short* __restrict__ Bt,
    const float* __restrict__ bias,
    const int* __restrict__ cnt,
    unsigned short* __restrict__ hout,
    float* __restrict__ out,
    const int* __restrict__ perm,
    const float* __restrict__ gate)
{
  __shared__ __align__(16) unsigned short As[128 * 64];
  __shared__ __align__(16) unsigned short Bs[128 * 64];

  const int e = blockIdx.z;
  int c = cnt[e]; if (c > CAPQ) c = CAPQ;
  const int row0 = blockIdx.y * 128;
  if (row0 >= c) return;                 // whole block exits together
  const int n0 = blockIdx.x * 128;

  const int tid = threadIdx.x;
  const int wid = tid >> 6, lane = tid & 63;
  const int wm = wid >> 1, wn = wid & 1;            // 2x2 wave grid, 64x64 per wave
  const int srow = wid * 32 + (lane >> 3);          // staging row (+ i*8)
  const int sk = (lane & 7) * 8;                    // staging k offset (16B granules)
  const int fr = lane & 15, fk = (lane >> 4) * 8;   // fragment row + k offset

  const unsigned short* Abase = A + ((size_t)e * CAPR + row0) * K;
  const unsigned short* Bbase = Bt + ((size_t)e * N + n0) * K;

  f32x4 acc[4][4];
#pragma unroll
  for (int m = 0; m < 4; ++m)
#pragma unroll
    for (int n = 0; n < 4; ++n) acc[m][n] = f32x4{0.f, 0.f, 0.f, 0.f};

  const int NT = K / 64;
  for (int t = 0; t < NT; ++t) {
    const int ko = t * 64;
#pragma unroll
    for (int i = 0; i < 4; ++i) {
      __builtin_amdgcn_global_load_lds(
          (glb_void*)(Abase + (size_t)(srow + i * 8) * K + ko + sk),
          (lds_void*)(&As[wid * 2048 + i * 512]), 16, 0, 0);
      __builtin_amdgcn_global_load_lds(
          (glb_void*)(Bbase + (size_t)(srow + i * 8) * K + ko + sk),
          (lds_void*)(&Bs[wid * 2048 + i * 512]), 16, 0, 0);
    }
    asm volatile("s_waitcnt vmcnt(0)" ::: "memory");
    __syncthreads();
#pragma unroll
    for (int kk = 0; kk < 2; ++kk) {
      bf16x8 af[4], bfm[4];
#pragma unroll
      for (int m = 0; m < 4; ++m)
        af[m] = *(const bf16x8*)(As + ((wm * 64 + m * 16 + fr) * 64 + kk * 32 + fk));
#pragma unroll
      for (int n = 0; n < 4; ++n)
        bfm[n] = *(const bf16x8*)(Bs + ((wn * 64 + n * 16 + fr) * 64 + kk * 32 + fk));
#pragma unroll
      for (int m = 0; m < 4; ++m)
#pragma unroll
        for (int n = 0; n < 4; ++n)
          acc[m][n] = __builtin_amdgcn_mfma_f32_16x16x32_bf16(af[m], bfm[n], acc[m][n], 0, 0, 0);
    }
    __syncthreads();
  }

  // epilogue: C layout col = lane&15, row = (lane>>4)*4 + j   [measured m89/m91]
  const int frow = (lane >> 4) * 4;
  const int fcol = lane & 15;
#pragma unroll
  for (int m = 0; m < 4; ++m) {
#pragma unroll
    for (int n = 0; n < 4; ++n) {
      const int col = n0 + wn * 64 + n * 16 + fcol;
      const float bv = bias[e * N + col];
      if (EPI == 0) {
#pragma unroll
        for (int j = 0; j < 4; ++j) {
          const int r = wm * 64 + m * 16 + frow + j;
          float v = acc[m][n][j] + bv;
          v = v > 0.f ? v : 0.f;
          hout[((size_t)e * CAPR + row0 + r) * N + col] = f2bf(v);
        }
      } else {
#pragma unroll
        for (int j = 0; j < 4; ++j) {
          const int r = row0 + wm * 64 + m * 16 + frow + j;
          const int tok = perm[e * CAPR + r];
          if (tok >= 0)
            out[(size_t)tok * N + col] = (acc[m][n][j] + bv) * gate[tok];
        }
      }
    }
  }
}

// ------------- finalize: entropy scalar + assignment counts -------------
__global__ void finalize_kernel(const float* __restrict__ entacc,
                                const int* __restrict__ cnt,
                                float* __restrict__ tail)
{
  const int i = threadIdx.x;
  if (i == 0) tail[0] = *entacc;
  if (i < E_NUM) tail[1 + i] = (float)cnt[i];
}

extern "C" void kernel_launch(void* const* d_in, const int* in_sizes, int n_in,
                              void* d_out, int out_size, void* d_ws, size_t ws_size,
                              hipStream_t stream) {
  const float* x  = (const float*)d_in[0];
  const float* rw = (const float*)d_in[1];
  const float* W1 = (const float*)d_in[2];
  const float* b1 = (const float*)d_in[3];
  const float* W2 = (const float*)d_in[4];
  const float* b2 = (const float*)d_in[5];
  float* out = (float*)d_out;

  char* ws = (char*)d_ws;
  size_t off = 0;
  auto alloc = [&](size_t bytes) -> void* {
    void* p = ws + off;
    off = (off + bytes + 255) & ~(size_t)255;
    return p;
  };
  // WT shared between W1T (GEMM1) and W2T (GEMM2) — transposed after GEMM1 finishes.
  unsigned short* WT   = (unsigned short*)alloc((size_t)E_NUM * D_DIM * H_DIM * 2); // 67 MB
  unsigned short* xs   = (unsigned short*)alloc((size_t)E_NUM * CAPR * D_DIM * 2);  // 21 MB
  unsigned short* h    = (unsigned short*)alloc((size_t)E_NUM * CAPR * H_DIM * 2);  // 80 MB
  float* gate   = (float*)alloc(T_TOK * 4);
  int*   perm   = (int*)alloc(E_NUM * CAPR * 4);
  int*   cnt    = (int*)alloc(256);
  float* entacc = (float*)alloc(256);

  hipMemsetAsync(d_out, 0, (size_t)out_size * 4, stream);          // dropped tokens -> 0
  hipMemsetAsync(xs, 0, (size_t)E_NUM * CAPR * D_DIM * 2, stream); // zero-pad tails
  hipMemsetAsync(perm, 0xFF, E_NUM * CAPR * 4, stream);            // -1 = invalid row
  hipMemsetAsync(cnt, 0, 256, stream);
  hipMemsetAsync(entacc, 0, 256, stream);

  router_dispatch_kernel<<<T_TOK / 4, 256, 0, stream>>>(x, rw, gate, cnt, entacc, perm, xs);

  // W1 [E][D][H] -> WT [E][H][D]
  transpose_conv<D_DIM, H_DIM><<<dim3(H_DIM / 64, D_DIM / 64, E_NUM), 256, 0, stream>>>(W1, WT);
  gemm_moe<D_DIM, H_DIM, 0><<<dim3(H_DIM / 128, MT_MAX, E_NUM), 256, 0, stream>>>(
      xs, WT, b1, cnt, h, nullptr, nullptr, nullptr);

  // W2 [E][H][D] -> WT [E][D][H]
  transpose_conv<H_DIM, D_DIM><<<dim3(D_DIM / 64, H_DIM / 64, E_NUM), 256, 0, stream>>>(W2, WT);
  gemm_moe<H_DIM, D_DIM, 1><<<dim3(D_DIM / 128, MT_MAX, E_NUM), 256, 0, stream>>>(
      h, WT, b2, cnt, nullptr, out, perm, gate);

  finalize_kernel<<<1, 64, 0, stream>>>(entacc, cnt, out + (size_t)T_TOK * D_DIM);
}